// Round 2
// baseline (12.714 us; speedup 1.0000x reference)
//
#include <hip/hip_runtime.h>

// SpatialAttentionLayer collapses algebraically because V = ones(B,L,O,d):
//  - X1 = V@W1+b1 is constant along the row index i
//  - => net[b,l,i,j] is constant in i => softmax over axis=-2 (i) is exactly 1/O
//  - => phi = psi = theta = 1/256 everywhere, independent of X
//  - V_ = V@W+b = c[d] := colsum(W)[d] + b[d], constant across (b,l,i)
//  - out = V_ + (3/O * ones) @ V_ = 4 * c[d], broadcast to (B,L,O,d)
//
// Round 1 -> 2: drop LDS + __syncthreads from the prologue. Each lane of a
// wave64 sums one column of W (row loads stay coalesced across lanes), then
// __shfl pulls the 4 c-values this lane stores. Stores issue one L2-latency
// earlier per block; no barrier, no LDS allocation (occupancy unconstrained).
// We are launch-overhead bound (~7us fixed vs 2.5us of writes), so this is
// the last shavable serial latency.

__global__ __launch_bounds__(256) void spa_const_broadcast(
    const float* __restrict__ W,   // (64,64) row-major: W[k*64 + d]
    const float* __restrict__ b,   // (64,)
    float4* __restrict__ out,      // out_size/4 float4s
    int total4) {
    const int t = threadIdx.x;
    const int lane = t & 63;

    // Lane `lane` computes c[lane] = 4 * (colsum(W)[lane] + b[lane]).
    // Loop over k: each iteration's 64 lane-loads cover one row of W,
    // consecutive addresses -> fully coalesced; W is 16 KB, L2-resident.
    float s = 0.0f;
    #pragma unroll
    for (int k = 0; k < 64; ++k) s += W[k * 64 + lane];
    const float c = 4.0f * (s + b[lane]);

    // float4 at flat index idx covers floats [4*idx, 4*idx+4) of a pattern
    // with period 64 floats (16 float4s). Grid stride is a multiple of 16,
    // so each thread's phase is fixed; pull the 4 components via shuffle.
    const int off = (lane & 15) * 4;
    const float4 v = make_float4(__shfl(c, off + 0, 64),
                                 __shfl(c, off + 1, 64),
                                 __shfl(c, off + 2, 64),
                                 __shfl(c, off + 3, 64));

    const int stride = gridDim.x * blockDim.x;
    for (int idx = blockIdx.x * blockDim.x + t; idx < total4; idx += stride) {
        out[idx] = v;
    }
}

extern "C" void kernel_launch(void* const* d_in, const int* in_sizes, int n_in,
                              void* d_out, int out_size, void* d_ws, size_t ws_size,
                              hipStream_t stream) {
    // inputs: 0:X 1:W1 2:b1 3:w2 4:b2 5:W 6:b   (only W, b matter)
    const float* W = (const float*)d_in[5];
    const float* b = (const float*)d_in[6];
    float* out = (float*)d_out;

    const int total4 = out_size / 4;  // 4,194,304 / 4 = 1,048,576
    const int threads = 256;
    const int blocks = 2048;          // 8 blocks/CU, 2 float4 stores/thread
    spa_const_broadcast<<<blocks, threads, 0, stream>>>(
        W, b, (float4*)out, total4);
}

// Round 3
// 11.031 us; speedup vs baseline: 1.1525x; 1.1525x over previous
//
#include <hip/hip_runtime.h>

// SpatialAttentionLayer collapses algebraically because V = ones(B,L,O,d):
//  - X1 = V@W1+b1 is constant along the row index i
//  - => net[b,l,i,j] is constant in i => softmax over axis=-2 (i) is exactly 1/O
//  - => phi = psi = theta = 1/256 everywhere, independent of X
//  - V_ = V@W+b = c[d] := colsum(W)[d] + b[d], constant across (b,l,i)
//  - out = V_ + (3/O * ones) @ V_ = 4 * c[d], broadcast to (B,L,O,d)
//
// Round 2 -> 3: round 2's all-lanes-sum-full-column quadrupled per-block W
// traffic (64 KB vs 16 KB) and regressed. Now: split the 64-row column sum
// across the 4 waves (16 rows each, 16 KB/block total), one LDS round-trip
// for the 4x64 partials, and 1024 blocks (halves redundant W reads again).
// Serial chain before stores: 16 loads + barrier instead of 64 loads.

__global__ __launch_bounds__(256) void spa_const_broadcast(
    const float* __restrict__ W,   // (64,64) row-major: W[k*64 + d]
    const float* __restrict__ b,   // (64,)
    float4* __restrict__ out,      // out_size/4 float4s
    int total4) {
    __shared__ float part[4][64];
    const int t = threadIdx.x;
    const int lane = t & 63;
    const int w = t >> 6;          // wave id 0..3

    // Wave w sums rows [16w, 16w+16) of column `lane`. Each row's 64 lane
    // loads are consecutive -> coalesced. Per-block W traffic: 16 KB.
    float s = 0.0f;
    #pragma unroll
    for (int k = 0; k < 16; ++k) s += W[(w * 16 + k) * 64 + lane];
    part[w][lane] = s;
    __syncthreads();

    // float4 at flat idx covers floats [4*idx,4*idx+4) of a 64-float-period
    // pattern; grid stride is a multiple of 16 float4s so phase is fixed.
    const int off = (lane & 15) * 4;
    float4 v;
    float* vp = &v.x;
    #pragma unroll
    for (int j = 0; j < 4; ++j) {
        const int d = off + j;
        vp[j] = 4.0f * (part[0][d] + part[1][d] + part[2][d] + part[3][d]
                        + b[d]);
    }

    const int stride = gridDim.x * blockDim.x;
    for (int idx = blockIdx.x * blockDim.x + t; idx < total4; idx += stride) {
        out[idx] = v;
    }
}

extern "C" void kernel_launch(void* const* d_in, const int* in_sizes, int n_in,
                              void* d_out, int out_size, void* d_ws, size_t ws_size,
                              hipStream_t stream) {
    // inputs: 0:X 1:W1 2:b1 3:w2 4:b2 5:W 6:b   (only W, b matter)
    const float* W = (const float*)d_in[5];
    const float* b = (const float*)d_in[6];
    float* out = (float*)d_out;

    const int total4 = out_size / 4;  // 4,194,304 / 4 = 1,048,576
    const int threads = 256;
    const int blocks = 1024;          // 4/CU; 4 float4 stores per thread
    spa_const_broadcast<<<blocks, threads, 0, stream>>>(
        W, b, (float4*)out, total4);
}